// Round 9
// baseline (245.064 us; speedup 1.0000x reference)
//
#include <hip/hip_runtime.h>
#include <math.h>
#include <stdint.h>

#define VOCAB 119547
#define NB    64
#define NS    512
#define NH    768
#define M_TOT (NB * NS)   // 32768

typedef _Float16 half8_t __attribute__((ext_vector_type(8)));
typedef _Float16 half4_t __attribute__((ext_vector_type(4)));
typedef float f32x4 __attribute__((ext_vector_type(4)));

#define WAITVM(N) asm volatile("s_waitcnt vmcnt(" #N ")" ::: "memory")
#define WAITLGKM() asm volatile("s_waitcnt lgkmcnt(0)" ::: "memory")
#define SCHEDB() __builtin_amdgcn_sched_barrier(0)

// ---------------------------------------------------------------------------
// global -> LDS async 16B copy. LDS dest = wave-uniform base + lane*16.
// ---------------------------------------------------------------------------
__device__ __forceinline__ void gload_lds16(const void* g, void* l) {
    __builtin_amdgcn_global_load_lds(
        (const __attribute__((address_space(1))) uint32_t*)g,
        (__attribute__((address_space(3))) uint32_t*)l, 16, 0, 0);
}

// ---------------------------------------------------------------------------
// prep: X -> Xh fp16 (16B stores) + W1 -> W1T fp16 transpose.
// (sparse/imp zeroing handled by hipMemsetAsync.)
// ---------------------------------------------------------------------------
__global__ void prep(const float* __restrict__ X, const float* __restrict__ W1,
                     _Float16* __restrict__ Xh, _Float16* __restrict__ W1T) {
    long i = (long)blockIdx.x * blockDim.x + threadIdx.x;
    long stride = (long)gridDim.x * blockDim.x;
    const long nx8 = (long)M_TOT * NH / 8;           // 3,145,728
    const float4* X4 = (const float4*)X;
    half8_t* Xh8 = (half8_t*)Xh;
    for (long j = i; j < nx8; j += stride) {
        float4 a = X4[2 * j], b = X4[2 * j + 1];
        half8_t h;
        h[0] = (_Float16)a.x; h[1] = (_Float16)a.y;
        h[2] = (_Float16)a.z; h[3] = (_Float16)a.w;
        h[4] = (_Float16)b.x; h[5] = (_Float16)b.y;
        h[6] = (_Float16)b.z; h[7] = (_Float16)b.w;
        Xh8[j] = h;
    }
    const long nw8 = (long)NH * NH / 8;              // 73,728
    half8_t* W1T8 = (half8_t*)W1T;
    for (long j = i; j < nw8; j += stride) {
        int n  = (int)(j / (NH / 8));
        int k8 = (int)(j % (NH / 8)) * 8;
        half8_t h;
#pragma unroll
        for (int q = 0; q < 8; ++q) h[q] = (_Float16)W1[(long)(k8 + q) * NH + n];
        W1T8[j] = h;
    }
}

// ---------------------------------------------------------------------------
// FP16 MFMA GEMM + relu/W2 epilogue. 128x128 tile, BK=32, 4 waves.
// 4-deep LDS pipeline with counted vmcnt: stage(T+3) issued at step T,
// waited at end of step T+2 -> TWO K-steps of latency cover (~900cy HBM-miss
// covered). One raw s_barrier per step; vmcnt never 0 in the main loop.
// ---------------------------------------------------------------------------
__global__ __launch_bounds__(256, 2) void gemm_f16(
    const _Float16* __restrict__ Xh,    // [M_TOT, NH] fp16
    const _Float16* __restrict__ W1T,   // [NH rows=n][NH k] fp16
    const float* __restrict__ b1,
    const float* __restrict__ W2v,
    float* __restrict__ imp)
{
    __shared__ __align__(16) _Float16 As[4][128 * 32];
    __shared__ __align__(16) _Float16 Bs[4][128 * 32];

    const int tid  = threadIdx.x;
    const int lane = tid & 63;
    const int wid  = tid >> 6;
    const int wm   = wid >> 1;
    const int wn   = wid & 1;

    // XCD-bijective swizzle (nwg = 1536 = 8*192), n-tile fastest so 6
    // consecutive wg share the same Xh panel in one XCD's L2.
    const int bid = blockIdx.x;
    const int wg  = (bid & 7) * 192 + (bid >> 3);
    const int nt  = wg % 6;
    const int mt  = wg / 6;
    const int m0  = mt * 128;
    const int n0  = nt * 128;

    // staging: 512 chunks of 16B per operand; thread t -> chunks t, t+256.
    // source-side XOR swizzle (rule #21): global k-chunk (c&3)^((r>>1)&3)
    // lands at linear LDS chunk c.
    const int c0 = tid, c1 = tid + 256;
    const int r0 = c0 >> 2, r1 = c1 >> 2;
    const int sk0 = ((c0 & 3) ^ ((r0 >> 1) & 3)) * 8;
    const int sk1 = ((c1 & 3) ^ ((r1 >> 1) & 3)) * 8;
    const _Float16* gA0 = Xh  + (long)(m0 + r0) * NH + sk0;
    const _Float16* gA1 = Xh  + (long)(m0 + r1) * NH + sk1;
    const _Float16* gB0 = W1T + (long)(n0 + r0) * NH + sk0;
    const _Float16* gB1 = W1T + (long)(n0 + r1) * NH + sk1;

    // fragment read offsets (inverse of the same swizzle)
    const int lr = lane & 15;
    const int ls = lane >> 4;
    const int s2 = ls ^ ((lr >> 1) & 3);
    int offA[4], offB[4];
#pragma unroll
    for (int f = 0; f < 4; ++f) {
        offA[f] = (wm * 64 + f * 16 + lr) * 32 + s2 * 8;
        offB[f] = (wn * 64 + f * 16 + lr) * 32 + s2 * 8;
    }

    f32x4 acc[4][4];
#pragma unroll
    for (int a = 0; a < 4; ++a)
#pragma unroll
        for (int b = 0; b < 4; ++b) acc[a][b] = (f32x4){0.f, 0.f, 0.f, 0.f};

#define STAGE(T, BUF)                                                       \
    gload_lds16(gA0 + (T) * 32, As[BUF] + c0 * 8);                          \
    gload_lds16(gA1 + (T) * 32, As[BUF] + c1 * 8);                          \
    gload_lds16(gB0 + (T) * 32, Bs[BUF] + c0 * 8);                          \
    gload_lds16(gB1 + (T) * 32, Bs[BUF] + c1 * 8);

#define COMPUTE(BUF)                                                        \
    {                                                                       \
        half8_t af[4], bf[4];                                               \
        _Pragma("unroll") for (int f = 0; f < 4; ++f)                       \
            af[f] = *(const half8_t*)(As[BUF] + offA[f]);                   \
        _Pragma("unroll") for (int f = 0; f < 4; ++f)                       \
            bf[f] = *(const half8_t*)(Bs[BUF] + offB[f]);                   \
        _Pragma("unroll") for (int a = 0; a < 4; ++a)                       \
            _Pragma("unroll") for (int b = 0; b < 4; ++b)                   \
                acc[a][b] = __builtin_amdgcn_mfma_f32_16x16x32_f16(         \
                    af[a], bf[b], acc[a][b], 0, 0, 0);                      \
    }

    // Steady-state step T (compute buf T&3):
    //   entering queue = [stage(T+1):4, stage(T+2):4]
    //   STAGE(T+3 -> buf (T+3)&3)  (that buf's reader was step T-1, done)
    //   COMPUTE(T&3)
    //   vmcnt(8): stage(T+1) retired (issued at step T-2 -> 2-step cover)
    //   s_barrier
#define KSTEP(TSTG, CURB, STGB)                                             \
    STAGE(TSTG, STGB);                                                      \
    SCHEDB();                                                               \
    COMPUTE(CURB);                                                          \
    WAITVM(8);                                                              \
    WAITLGKM();                                                             \
    __builtin_amdgcn_s_barrier();                                           \
    SCHEDB();

    // ---- prologue: stage tiles 0,1,2 ----
    STAGE(0, 0);          // queue 4
    STAGE(1, 1);          // queue 8
    STAGE(2, 2);          // queue 12
    WAITVM(8);            // stage(0) done; 1,2 in flight
    WAITLGKM();
    __builtin_amdgcn_s_barrier();
    SCHEDB();

    // ---- main loop: steps 0..19 (5 x 4, static buffer indices) ----
#pragma unroll 1
    for (int tt = 0; tt < 5; ++tt) {
        const int t4 = 4 * tt;
        KSTEP(t4 + 3, 0, 3);      // step 4tt   : compute b0, stage->b3
        KSTEP(t4 + 4, 1, 0);      // step 4tt+1 : compute b1, stage->b0
        KSTEP(t4 + 5, 2, 1);      // step 4tt+2 : compute b2, stage->b1
        KSTEP(t4 + 6, 3, 2);      // step 4tt+3 : compute b3, stage->b2
    }
    // ---- tail: steps 20..23 (stage 23 at step 20; drain 8 -> 4 -> 0) ----
    KSTEP(23, 0, 3);              // step 20: compute b0, stage 23 -> b3
    COMPUTE(1);                   // step 21
    WAITVM(4);                    // stage(22) done
    WAITLGKM();
    __builtin_amdgcn_s_barrier();
    SCHEDB();
    COMPUTE(2);                   // step 22
    WAITVM(0);                    // stage(23) done
    WAITLGKM();
    __builtin_amdgcn_s_barrier();
    SCHEDB();
    COMPUTE(3);                   // step 23

#undef STAGE
#undef COMPUTE
#undef KSTEP

    // ---- epilogue: +b1, relu, *W2, reduce over n, atomicAdd per row ----
    // C/D layout (m89): col = lane&15 (n), row = (lane>>4)*4 + reg (m).
    float b1v[4], w2v[4];
#pragma unroll
    for (int f = 0; f < 4; ++f) {
        int col = n0 + wn * 64 + f * 16 + lr;
        b1v[f] = b1[col];
        w2v[f] = W2v[col];
    }
#pragma unroll
    for (int a = 0; a < 4; ++a)
#pragma unroll
        for (int reg = 0; reg < 4; ++reg) {
            float p = 0.f;
#pragma unroll
            for (int f = 0; f < 4; ++f) {
                float h = fmaxf(acc[a][f][reg] + b1v[f], 0.f);
                p = fmaf(h, w2v[f], p);
            }
            p += __shfl_xor(p, 1);
            p += __shfl_xor(p, 2);
            p += __shfl_xor(p, 4);
            p += __shfl_xor(p, 8);
            if (lr == 0) {
                int row = m0 + wm * 64 + a * 16 + ls * 4 + reg;
                atomicAdd(&imp[row], p);
            }
        }
}

// ---------------------------------------------------------------------------
// finalize: token_weights + scatter-max (uint atomicMax exact for >=0 floats)
// ---------------------------------------------------------------------------
__global__ void finalize(const float* __restrict__ imp,
                         const float* __restrict__ b2,
                         const int* __restrict__ mask,
                         const int* __restrict__ ids,
                         float* __restrict__ tw_out,
                         float* __restrict__ sparse) {
    int i = blockIdx.x * blockDim.x + threadIdx.x;
    if (i >= M_TOT) return;
    float v = fmaxf(imp[i] + b2[0], 0.f);
    float tw = log1pf(v) * (float)mask[i];
    tw_out[i] = tw;
    int b  = i >> 9;
    int id = ids[i];
    unsigned int* addr = (unsigned int*)&sparse[(long)b * VOCAB + id];
    atomicMax(addr, __float_as_uint(tw));
}

// ======================= fallback fp32 path (proven) =======================
__global__ __launch_bounds__(256) void gemm_importance(
    const float* __restrict__ X, const float* __restrict__ W1,
    const float* __restrict__ b1, const float* __restrict__ W2v,
    float* __restrict__ imp)
{
    __shared__ float As_[16][64];
    __shared__ float Bs_[16][128];
    const int tid = threadIdx.x;
    const int m0 = blockIdx.x * 64, n0 = blockIdx.y * 128;
    const int tx = tid & 31, ty = tid >> 5;
    float acc[8][4];
#pragma unroll
    for (int r = 0; r < 8; ++r)
#pragma unroll
        for (int c = 0; c < 4; ++c) acc[r][c] = 0.f;
    const int arow = tid >> 2, ac = (tid & 3) * 4;
    const float* Xp = X + (long)(m0 + arow) * NH + ac;
    for (int k0 = 0; k0 < NH; k0 += 16) {
        float4 av = *(const float4*)(Xp + k0);
        As_[ac + 0][arow] = av.x; As_[ac + 1][arow] = av.y;
        As_[ac + 2][arow] = av.z; As_[ac + 3][arow] = av.w;
        int f = tid, br = f >> 5, bc = (f & 31) * 4;
        *(float4*)&Bs_[br][bc] = *(const float4*)&W1[(long)(k0 + br) * NH + n0 + bc];
        f = tid + 256; br = f >> 5; bc = (f & 31) * 4;
        *(float4*)&Bs_[br][bc] = *(const float4*)&W1[(long)(k0 + br) * NH + n0 + bc];
        __syncthreads();
#pragma unroll
        for (int k = 0; k < 16; ++k) {
            float4 a0 = *(const float4*)&As_[k][ty * 8];
            float4 a1 = *(const float4*)&As_[k][ty * 8 + 4];
            float4 bv = *(const float4*)&Bs_[k][tx * 4];
            float a[8] = {a0.x, a0.y, a0.z, a0.w, a1.x, a1.y, a1.z, a1.w};
            float bb[4] = {bv.x, bv.y, bv.z, bv.w};
#pragma unroll
            for (int r = 0; r < 8; ++r)
#pragma unroll
                for (int c = 0; c < 4; ++c)
                    acc[r][c] = fmaf(a[r], bb[c], acc[r][c]);
        }
        __syncthreads();
    }
    float b1v[4], w2v[4];
#pragma unroll
    for (int c = 0; c < 4; ++c) {
        int col = n0 + tx * 4 + c;
        b1v[c] = b1[col]; w2v[c] = W2v[col];
    }
#pragma unroll
    for (int r = 0; r < 8; ++r) {
        float p = 0.f;
#pragma unroll
        for (int c = 0; c < 4; ++c)
            p = fmaf(fmaxf(acc[r][c] + b1v[c], 0.f), w2v[c], p);
#pragma unroll
        for (int mdel = 16; mdel >= 1; mdel >>= 1) p += __shfl_xor(p, mdel);
        if (tx == 0) atomicAdd(&imp[m0 + ty * 8 + r], p);
    }
}

// ---------------------------------------------------------------------------
extern "C" void kernel_launch(void* const* d_in, const int* in_sizes, int n_in,
                              void* d_out, int out_size, void* d_ws, size_t ws_size,
                              hipStream_t stream) {
    const float* X    = (const float*)d_in[0];
    const int*   ids  = (const int*)d_in[1];   // int64 in ref -> int32 on device
    const int*   mask = (const int*)d_in[2];
    const float* W1   = (const float*)d_in[3];
    const float* b1   = (const float*)d_in[4];
    const float* W2   = (const float*)d_in[5];
    const float* b2   = (const float*)d_in[6];

    float* sparse = (float*)d_out;                    // [64, VOCAB]
    float* tw_out = sparse + (long)NB * VOCAB;        // [64, 512]
    float* imp    = (float*)d_ws;                     // [32768] f32 at offset 0

    const size_t impB = (size_t)M_TOT * 4;            // 131072
    const size_t XhB  = (size_t)M_TOT * NH * 2;       // 50,331,648
    const size_t W1TB = (size_t)NH * NH * 2;          // 1,179,648

    hipMemsetAsync(sparse, 0, (size_t)NB * VOCAB * 4, stream);
    hipMemsetAsync(imp, 0, impB, stream);

    if (ws_size >= impB + XhB + W1TB) {
        _Float16* Xh  = (_Float16*)((char*)d_ws + impB);
        _Float16* W1T = (_Float16*)((char*)d_ws + impB + XhB);
        prep<<<2048, 256, 0, stream>>>(X, W1, Xh, W1T);
        gemm_f16<<<(M_TOT / 128) * (NH / 128), 256, 0, stream>>>(
            Xh, W1T, b1, W2, imp);
    } else {
        dim3 grid(M_TOT / 64, NH / 128);
        gemm_importance<<<grid, 256, 0, stream>>>(X, W1, b1, W2, imp);
    }
    finalize<<<M_TOT / 256, 256, 0, stream>>>(imp, b2, mask, ids, tw_out, sparse);
}

// Round 10
// 236.239 us; speedup vs baseline: 1.0374x; 1.0374x over previous
//
#include <hip/hip_runtime.h>
#include <math.h>
#include <stdint.h>

#define VOCAB 119547
#define NB    64
#define NS    512
#define NH    768
#define M_TOT (NB * NS)   // 32768

typedef _Float16 half8_t __attribute__((ext_vector_type(8)));
typedef _Float16 half4_t __attribute__((ext_vector_type(4)));
typedef float f32x4 __attribute__((ext_vector_type(4)));

#define WAITVM(N) asm volatile("s_waitcnt vmcnt(" #N ")" ::: "memory")
#define WAITLGKM() asm volatile("s_waitcnt lgkmcnt(0)" ::: "memory")
#define SCHEDB() __builtin_amdgcn_sched_barrier(0)

// ---------------------------------------------------------------------------
// global -> LDS async 16B copy. LDS dest = wave-uniform base + lane*16.
// ---------------------------------------------------------------------------
__device__ __forceinline__ void gload_lds16(const void* g, void* l) {
    __builtin_amdgcn_global_load_lds(
        (const __attribute__((address_space(1))) uint32_t*)g,
        (__attribute__((address_space(3))) uint32_t*)l, 16, 0, 0);
}

// ---------------------------------------------------------------------------
// prep_all: zero sparse + imp (replaces both hipMemsetAsync dispatches,
// overlapping the zero-stores with the conversion streams), convert
// X -> Xh fp16 (16B stores), transpose W1 -> W1T fp16.
// ---------------------------------------------------------------------------
__global__ void prep_all(const float* __restrict__ X, const float* __restrict__ W1,
                         float4* __restrict__ sparse4, float4* __restrict__ imp4,
                         _Float16* __restrict__ Xh, _Float16* __restrict__ W1T) {
    long i = (long)blockIdx.x * blockDim.x + threadIdx.x;
    long stride = (long)gridDim.x * blockDim.x;
    const float4 z = make_float4(0.f, 0.f, 0.f, 0.f);
    // zero sparse: 64*119547 floats = 1,912,752 float4
    const long nsp4 = (long)NB * VOCAB / 4;
    for (long j = i; j < nsp4; j += stride) sparse4[j] = z;
    // zero imp: 8192 float4
    for (long j = i; j < M_TOT / 4; j += stride) imp4[j] = z;
    // X: 8 floats -> half8 per iter (32B load, 16B store, coalesced)
    const long nx8 = (long)M_TOT * NH / 8;           // 3,145,728
    const float4* X4 = (const float4*)X;
    half8_t* Xh8 = (half8_t*)Xh;
    for (long j = i; j < nx8; j += stride) {
        float4 a = X4[2 * j], b = X4[2 * j + 1];
        half8_t h;
        h[0] = (_Float16)a.x; h[1] = (_Float16)a.y;
        h[2] = (_Float16)a.z; h[3] = (_Float16)a.w;
        h[4] = (_Float16)b.x; h[5] = (_Float16)b.y;
        h[6] = (_Float16)b.z; h[7] = (_Float16)b.w;
        Xh8[j] = h;
    }
    // W1T[n][k] = (f16) W1[k][n], 8 k per thread -> 16B store
    const long nw8 = (long)NH * NH / 8;              // 73,728
    half8_t* W1T8 = (half8_t*)W1T;
    for (long j = i; j < nw8; j += stride) {
        int n  = (int)(j / (NH / 8));
        int k8 = (int)(j % (NH / 8)) * 8;
        half8_t h;
#pragma unroll
        for (int q = 0; q < 8; ++q) h[q] = (_Float16)W1[(long)(k8 + q) * NH + n];
        W1T8[j] = h;
    }
}

// ---------------------------------------------------------------------------
// FP16 MFMA GEMM + relu/W2 epilogue. R8-proven: 128x128 tile, BK=32, 4 waves,
// 3-deep LDS pipeline, counted vmcnt (stage(T+2) issued at step T, waited at
// end of step T+1), one raw s_barrier per K-step, vmcnt never 0 in the loop.
// Measured: 62 us, MfmaUtil 24.6%, 0 bank conflicts.
// ---------------------------------------------------------------------------
__global__ __launch_bounds__(256, 3) void gemm_f16(
    const _Float16* __restrict__ Xh,    // [M_TOT, NH] fp16
    const _Float16* __restrict__ W1T,   // [NH rows=n][NH k] fp16
    const float* __restrict__ b1,
    const float* __restrict__ W2v,
    float* __restrict__ imp)
{
    __shared__ __align__(16) _Float16 As[3][128 * 32];
    __shared__ __align__(16) _Float16 Bs[3][128 * 32];

    const int tid  = threadIdx.x;
    const int lane = tid & 63;
    const int wid  = tid >> 6;
    const int wm   = wid >> 1;
    const int wn   = wid & 1;

    // XCD-bijective swizzle (nwg = 1536 = 8*192), n-tile fastest so 6
    // consecutive wg share the same Xh panel in one XCD's L2.
    const int bid = blockIdx.x;
    const int wg  = (bid & 7) * 192 + (bid >> 3);
    const int nt  = wg % 6;
    const int mt  = wg / 6;
    const int m0  = mt * 128;
    const int n0  = nt * 128;

    // staging: 512 chunks of 16B per operand; thread t -> chunks t, t+256.
    // source-side XOR swizzle (rule #21): global k-chunk (c&3)^((r>>1)&3)
    // lands at linear LDS chunk c.
    const int c0 = tid, c1 = tid + 256;
    const int r0 = c0 >> 2, r1 = c1 >> 2;
    const int sk0 = ((c0 & 3) ^ ((r0 >> 1) & 3)) * 8;
    const int sk1 = ((c1 & 3) ^ ((r1 >> 1) & 3)) * 8;
    const _Float16* gA0 = Xh  + (long)(m0 + r0) * NH + sk0;
    const _Float16* gA1 = Xh  + (long)(m0 + r1) * NH + sk1;
    const _Float16* gB0 = W1T + (long)(n0 + r0) * NH + sk0;
    const _Float16* gB1 = W1T + (long)(n0 + r1) * NH + sk1;

    // fragment read offsets (inverse of the same swizzle)
    const int lr = lane & 15;
    const int ls = lane >> 4;
    const int s2 = ls ^ ((lr >> 1) & 3);
    int offA[4], offB[4];
#pragma unroll
    for (int f = 0; f < 4; ++f) {
        offA[f] = (wm * 64 + f * 16 + lr) * 32 + s2 * 8;
        offB[f] = (wn * 64 + f * 16 + lr) * 32 + s2 * 8;
    }

    f32x4 acc[4][4];
#pragma unroll
    for (int a = 0; a < 4; ++a)
#pragma unroll
        for (int b = 0; b < 4; ++b) acc[a][b] = (f32x4){0.f, 0.f, 0.f, 0.f};

#define STAGE(T, BUF)                                                       \
    gload_lds16(gA0 + (T) * 32, As[BUF] + c0 * 8);                          \
    gload_lds16(gA1 + (T) * 32, As[BUF] + c1 * 8);                          \
    gload_lds16(gB0 + (T) * 32, Bs[BUF] + c0 * 8);                          \
    gload_lds16(gB1 + (T) * 32, Bs[BUF] + c1 * 8);

#define COMPUTE(BUF)                                                        \
    {                                                                       \
        half8_t af[4], bf[4];                                               \
        _Pragma("unroll") for (int f = 0; f < 4; ++f)                       \
            af[f] = *(const half8_t*)(As[BUF] + offA[f]);                   \
        _Pragma("unroll") for (int f = 0; f < 4; ++f)                       \
            bf[f] = *(const half8_t*)(Bs[BUF] + offB[f]);                   \
        _Pragma("unroll") for (int a = 0; a < 4; ++a)                       \
            _Pragma("unroll") for (int b = 0; b < 4; ++b)                   \
                acc[a][b] = __builtin_amdgcn_mfma_f32_16x16x32_f16(         \
                    af[a], bf[b], acc[a][b], 0, 0, 0);                      \
    }

#define KSTEP(TSTG, CURB, STGB)                                             \
    STAGE(TSTG, STGB);                                                      \
    SCHEDB();                                                               \
    COMPUTE(CURB);                                                          \
    WAITVM(4);                                                              \
    WAITLGKM();                                                             \
    __builtin_amdgcn_s_barrier();                                           \
    SCHEDB();

    // ---- prologue ----
    STAGE(0, 0);          // queue 4
    STAGE(1, 1);          // queue 8
    WAITVM(4);            // stage(0) done; stage(1) in flight
    WAITLGKM();
    __builtin_amdgcn_s_barrier();
    SCHEDB();

    // ---- main loop: steps 0..20 (7 x 3, static buffer indices) ----
#pragma unroll 1
    for (int tt = 0; tt < 7; ++tt) {
        const int t3 = 3 * tt;
        KSTEP(t3 + 2, 0, 2);      // step 3tt   : compute b0, stage->b2
        KSTEP(t3 + 3, 1, 0);      // step 3tt+1 : compute b1, stage->b0
        KSTEP(t3 + 4, 2, 1);      // step 3tt+2 : compute b2, stage->b1
    }
    // ---- tail: steps 21, 22, 23 ----
    KSTEP(23, 0, 2);              // step 21: compute b0, stage 23 -> b2
    COMPUTE(1);                   // step 22: compute b1
    WAITVM(0);                    // stage(23) landed
    WAITLGKM();
    __builtin_amdgcn_s_barrier();
    SCHEDB();
    COMPUTE(2);                   // step 23: compute b2

#undef STAGE
#undef COMPUTE
#undef KSTEP

    // ---- epilogue: +b1, relu, *W2, reduce over n, atomicAdd per row ----
    // C/D layout (m89): col = lane&15 (n), row = (lane>>4)*4 + reg (m).
    float b1v[4], w2v[4];
#pragma unroll
    for (int f = 0; f < 4; ++f) {
        int col = n0 + wn * 64 + f * 16 + lr;
        b1v[f] = b1[col];
        w2v[f] = W2v[col];
    }
#pragma unroll
    for (int a = 0; a < 4; ++a)
#pragma unroll
        for (int reg = 0; reg < 4; ++reg) {
            float p = 0.f;
#pragma unroll
            for (int f = 0; f < 4; ++f) {
                float h = fmaxf(acc[a][f][reg] + b1v[f], 0.f);
                p = fmaf(h, w2v[f], p);
            }
            p += __shfl_xor(p, 1);
            p += __shfl_xor(p, 2);
            p += __shfl_xor(p, 4);
            p += __shfl_xor(p, 8);
            if (lr == 0) {
                int row = m0 + wm * 64 + a * 16 + ls * 4 + reg;
                atomicAdd(&imp[row], p);
            }
        }
}

// ---------------------------------------------------------------------------
// finalize: token_weights + scatter-max (uint atomicMax exact for >=0 floats)
// ---------------------------------------------------------------------------
__global__ void finalize(const float* __restrict__ imp,
                         const float* __restrict__ b2,
                         const int* __restrict__ mask,
                         const int* __restrict__ ids,
                         float* __restrict__ tw_out,
                         float* __restrict__ sparse) {
    int i = blockIdx.x * blockDim.x + threadIdx.x;
    if (i >= M_TOT) return;
    float v = fmaxf(imp[i] + b2[0], 0.f);
    float tw = log1pf(v) * (float)mask[i];
    tw_out[i] = tw;
    int b  = i >> 9;
    int id = ids[i];
    unsigned int* addr = (unsigned int*)&sparse[(long)b * VOCAB + id];
    atomicMax(addr, __float_as_uint(tw));
}

// ======================= fallback fp32 path (proven) =======================
__global__ __launch_bounds__(256) void gemm_importance(
    const float* __restrict__ X, const float* __restrict__ W1,
    const float* __restrict__ b1, const float* __restrict__ W2v,
    float* __restrict__ imp)
{
    __shared__ float As_[16][64];
    __shared__ float Bs_[16][128];
    const int tid = threadIdx.x;
    const int m0 = blockIdx.x * 64, n0 = blockIdx.y * 128;
    const int tx = tid & 31, ty = tid >> 5;
    float acc[8][4];
#pragma unroll
    for (int r = 0; r < 8; ++r)
#pragma unroll
        for (int c = 0; c < 4; ++c) acc[r][c] = 0.f;
    const int arow = tid >> 2, ac = (tid & 3) * 4;
    const float* Xp = X + (long)(m0 + arow) * NH + ac;
    for (int k0 = 0; k0 < NH; k0 += 16) {
        float4 av = *(const float4*)(Xp + k0);
        As_[ac + 0][arow] = av.x; As_[ac + 1][arow] = av.y;
        As_[ac + 2][arow] = av.z; As_[ac + 3][arow] = av.w;
        int f = tid, br = f >> 5, bc = (f & 31) * 4;
        *(float4*)&Bs_[br][bc] = *(const float4*)&W1[(long)(k0 + br) * NH + n0 + bc];
        f = tid + 256; br = f >> 5; bc = (f & 31) * 4;
        *(float4*)&Bs_[br][bc] = *(const float4*)&W1[(long)(k0 + br) * NH + n0 + bc];
        __syncthreads();
#pragma unroll
        for (int k = 0; k < 16; ++k) {
            float4 a0 = *(const float4*)&As_[k][ty * 8];
            float4 a1 = *(const float4*)&As_[k][ty * 8 + 4];
            float4 bv = *(const float4*)&Bs_[k][tx * 4];
            float a[8] = {a0.x, a0.y, a0.z, a0.w, a1.x, a1.y, a1.z, a1.w};
            float bb[4] = {bv.x, bv.y, bv.z, bv.w};
#pragma unroll
            for (int r = 0; r < 8; ++r)
#pragma unroll
                for (int c = 0; c < 4; ++c)
                    acc[r][c] = fmaf(a[r], bb[c], acc[r][c]);
        }
        __syncthreads();
    }
    float b1v[4], w2v[4];
#pragma unroll
    for (int c = 0; c < 4; ++c) {
        int col = n0 + tx * 4 + c;
        b1v[c] = b1[col]; w2v[c] = W2v[col];
    }
#pragma unroll
    for (int r = 0; r < 8; ++r) {
        float p = 0.f;
#pragma unroll
        for (int c = 0; c < 4; ++c)
            p = fmaf(fmaxf(acc[r][c] + b1v[c], 0.f), w2v[c], p);
#pragma unroll
        for (int mdel = 16; mdel >= 1; mdel >>= 1) p += __shfl_xor(p, mdel);
        if (tx == 0) atomicAdd(&imp[m0 + ty * 8 + r], p);
    }
}

// ---------------------------------------------------------------------------
extern "C" void kernel_launch(void* const* d_in, const int* in_sizes, int n_in,
                              void* d_out, int out_size, void* d_ws, size_t ws_size,
                              hipStream_t stream) {
    const float* X    = (const float*)d_in[0];
    const int*   ids  = (const int*)d_in[1];   // int64 in ref -> int32 on device
    const int*   mask = (const int*)d_in[2];
    const float* W1   = (const float*)d_in[3];
    const float* b1   = (const float*)d_in[4];
    const float* W2   = (const float*)d_in[5];
    const float* b2   = (const float*)d_in[6];

    float* sparse = (float*)d_out;                    // [64, VOCAB]
    float* tw_out = sparse + (long)NB * VOCAB;        // [64, 512]
    float* imp    = (float*)d_ws;                     // [32768] f32 at offset 0

    const size_t impB = (size_t)M_TOT * 4;            // 131072
    const size_t XhB  = (size_t)M_TOT * NH * 2;       // 50,331,648
    const size_t W1TB = (size_t)NH * NH * 2;          // 1,179,648

    if (ws_size >= impB + XhB + W1TB) {
        _Float16* Xh  = (_Float16*)((char*)d_ws + impB);
        _Float16* W1T = (_Float16*)((char*)d_ws + impB + XhB);
        prep_all<<<4096, 256, 0, stream>>>(X, W1, (float4*)sparse, (float4*)imp,
                                           Xh, W1T);
        gemm_f16<<<(M_TOT / 128) * (NH / 128), 256, 0, stream>>>(
            Xh, W1T, b1, W2, imp);
    } else {
        hipMemsetAsync(sparse, 0, (size_t)NB * VOCAB * 4, stream);
        hipMemsetAsync(imp, 0, impB, stream);
        dim3 grid(M_TOT / 64, NH / 128);
        gemm_importance<<<grid, 256, 0, stream>>>(X, W1, b1, W2, imp);
    }
    finalize<<<M_TOT / 256, 256, 0, stream>>>(imp, b2, mask, ids, tw_out, sparse);
}